// Round 5
// baseline (213.080 us; speedup 1.0000x reference)
//
#include <hip/hip_runtime.h>
#include <hip/hip_bf16.h>

typedef short short8 __attribute__((ext_vector_type(8)));
typedef float f32x4 __attribute__((ext_vector_type(4)));

#define GPTR(x) ((const __attribute__((address_space(1))) void*)(x))
#define LPTR(x) ((__attribute__((address_space(3))) void*)(x))

static __device__ __forceinline__ unsigned short f2bf(float f) {
  __hip_bfloat16 h = __float2bfloat16(f);
  return __builtin_bit_cast(unsigned short, h);
}
static __device__ __forceinline__ float bf2f(unsigned short u) {
  unsigned int v = ((unsigned int)u) << 16;
  return __builtin_bit_cast(float, v);
}

// ---------------- block reduction helper ----------------
static __device__ __forceinline__ void block_reduce2(float& s, float& q) {
#pragma unroll
  for (int o = 32; o > 0; o >>= 1) { s += __shfl_down(s, o); q += __shfl_down(q, o); }
  __shared__ float rs[4], rq[4];
  int tid = threadIdx.x;
  if ((tid & 63) == 0) { rs[tid >> 6] = s; rq[tid >> 6] = q; }
  __syncthreads();
  if (tid == 0) {
    s = rs[0] + rs[1] + rs[2] + rs[3];
    q = rq[0] + rq[1] + rq[2] + rq[3];
  }
}

// ---------------- fused prep (weights->bf16, mem-KV scatter) + GN1 stats stage 1 ----------------
__global__ __launch_bounds__(256) void prep_gn1_kernel(
    const float* __restrict__ wqkv, const float* __restrict__ wout,
    const float* __restrict__ memkv, const float* __restrict__ x,
    unsigned short* __restrict__ wq, unsigned short* __restrict__ wo,
    unsigned short* __restrict__ Kb, unsigned short* __restrict__ Vb,
    float2* __restrict__ part1) {
  int blk = blockIdx.x;
  if (blk < 4128) {
    int i = blk * 256 + threadIdx.x;
    if (i < 786432) {
      wq[i] = f2bf(wqkv[i]);
    } else if (i < 1048576) {
      int j = i - 786432;
      wo[j] = f2bf(wout[j]);
    } else if (i < 1056768) {
      int t = i - 1048576;  // (((s*2+b)*8+h)*4+j)*64+d
      int d = t & 63, j = (t >> 6) & 3, h = (t >> 8) & 7, b = (t >> 11) & 1, s = t >> 12;
      unsigned short bv = f2bf(memkv[((s * 8 + h) * 64 + d) * 4 + j]);
      unsigned short* dst = (s == 0) ? Kb : Vb;
      dst[((size_t)(b * 8 + h) * 2308 + j) * 64 + d] = bv;
    }
  } else {
    int bgc = blk - 4128;  // (b*32+g)*8 + chunk
    const float4* base = (const float4*)x + (size_t)bgc * 1152;
    float s = 0.f, q = 0.f;
    for (int i = threadIdx.x; i < 1152; i += 256) {
      float4 v = base[i];
      s += v.x + v.y + v.z + v.w;
      q += v.x * v.x + v.y * v.y + v.z * v.z + v.w * v.w;
    }
    block_reduce2(s, q);
    if (threadIdx.x == 0) part1[bgc] = make_float2(s, q);
  }
}

// ---------------- normalize + transpose -> t_bf16 (token-major); folds stats stage 2 ----------------
__global__ __launch_bounds__(256) void tnorm_kernel(const float* __restrict__ x,
    const float* __restrict__ gw, const float* __restrict__ gb,
    const float2* __restrict__ part1, unsigned short* __restrict__ t) {
  __shared__ float tile[32][33];
  int n0 = blockIdx.x * 32, c0 = blockIdx.y * 32, b = blockIdx.z;
  int g0 = c0 >> 4;
  float mu2[2], rs2[2];
#pragma unroll
  for (int gg = 0; gg < 2; gg++) {
    float s = 0.f, q = 0.f;
    const float2* p = part1 + (size_t)(b * 32 + g0 + gg) * 8;
#pragma unroll
    for (int k = 0; k < 8; k++) { float2 v = p[k]; s += v.x; q += v.y; }
    float mu = s / 36864.f;
    float var = q / 36864.f - mu * mu;
    mu2[gg] = mu;
    rs2[gg] = rsqrtf(var + 1e-5f);
  }
  int tx = threadIdx.x & 31, ty = threadIdx.x >> 5;
#pragma unroll
  for (int r = 0; r < 4; r++) {
    int c = c0 + ty + r * 8;
    tile[ty + r * 8][tx] = x[((size_t)(b * 512 + c)) * 2304 + n0 + tx];
  }
  __syncthreads();
  int gg = tx >> 4;
#pragma unroll
  for (int r = 0; r < 4; r++) {
    int n = n0 + ty + r * 8;
    int c = c0 + tx;
    float v = tile[tx][ty + r * 8];
    t[((size_t)(b * 2304 + n)) * 512 + c] = f2bf((v - mu2[gg]) * rs2[gg] * gw[c] + gb[c]);
  }
}

// ---------------- GEMM1: qkv = t @ wq^T, async LDS staging, scatter Q/K/V ----------------
__global__ __launch_bounds__(256) void gemm_qkv_kernel(
    const unsigned short* __restrict__ A, const unsigned short* __restrict__ Bw,
    unsigned short* __restrict__ Qb, unsigned short* __restrict__ Kb,
    unsigned short* __restrict__ Vb) {
  __shared__ __attribute__((aligned(16))) unsigned short As[128 * 32];
  __shared__ __attribute__((aligned(16))) unsigned short Bs[128 * 32];
  int m0 = blockIdx.x * 128, o0 = blockIdx.y * 128;
  int tid = threadIdx.x, lane = tid & 63, wave = tid >> 6;
  int quad = lane >> 4, l15 = lane & 15;
  int wm = wave & 1, wn = wave >> 1;
  f32x4 acc[4][4] = {};
  for (int k0 = 0; k0 < 512; k0 += 32) {
    __syncthreads();
#pragma unroll
    for (int c = 0; c < 2; c++) {
      int q = tid + c * 256;
      int row = q >> 2, cc = q & 3;
      __builtin_amdgcn_global_load_lds(GPTR(A + (size_t)(m0 + row) * 512 + k0 + cc * 8),
                                       LPTR(As + q * 8), 16, 0, 0);
      __builtin_amdgcn_global_load_lds(GPTR(Bw + (size_t)(o0 + row) * 512 + k0 + cc * 8),
                                       LPTR(Bs + q * 8), 16, 0, 0);
    }
    __syncthreads();
    short8 af[4], bf[4];
#pragma unroll
    for (int i = 0; i < 4; i++) af[i] = *(const short8*)(As + (wm * 64 + i * 16 + l15) * 32 + quad * 8);
#pragma unroll
    for (int j = 0; j < 4; j++) bf[j] = *(const short8*)(Bs + (wn * 64 + j * 16 + l15) * 32 + quad * 8);
#pragma unroll
    for (int i = 0; i < 4; i++)
#pragma unroll
      for (int j = 0; j < 4; j++)
        acc[i][j] = __builtin_amdgcn_mfma_f32_16x16x32_bf16(af[i], bf[j], acc[i][j], 0, 0, 0);
  }
#pragma unroll
  for (int i = 0; i < 4; i++) {
#pragma unroll
    for (int j = 0; j < 4; j++) {
      int colo = o0 + wn * 64 + j * 16 + l15;
      int part = colo >> 9, rr = colo & 511, h = rr >> 6, d = rr & 63;
#pragma unroll
      for (int reg = 0; reg < 4; reg++) {
        int m = m0 + wm * 64 + i * 16 + quad * 4 + reg;
        int b = (m >= 2304) ? 1 : 0;
        int n = m - b * 2304;
        unsigned short bv = f2bf(acc[i][j][reg]);
        if (part == 0)      Qb[((size_t)(b * 8 + h) * 2304 + n) * 64 + d] = bv;
        else if (part == 1) Kb[((size_t)(b * 8 + h) * 2308 + 4 + n) * 64 + d] = bv;
        else                Vb[((size_t)(b * 8 + h) * 2308 + 4 + n) * 64 + d] = bv;
      }
    }
  }
}

// ---------------- V transpose: Vb [bh][nk][64] -> Vt [bh][64][2368] ----------------
__global__ __launch_bounds__(256) void vt_kernel(const unsigned short* __restrict__ Vb,
                                                 unsigned short* __restrict__ Vt) {
  __shared__ unsigned short tile[64 * 68];
  int ct = blockIdx.x, bh = blockIdx.y;
  int tid = threadIdx.x;
#pragma unroll
  for (int c = 0; c < 2; c++) {
    int q = tid + c * 256;
    int row = q >> 3, c8 = q & 7;
    int gk = ct * 64 + row;
    uint4 v = make_uint4(0, 0, 0, 0);
    if (gk < 2308) v = *(const uint4*)(Vb + ((size_t)bh * 2308 + gk) * 64 + c8 * 8);
    *(uint2*)(tile + row * 68 + c8 * 8)     = make_uint2(v.x, v.y);
    *(uint2*)(tile + row * 68 + c8 * 8 + 4) = make_uint2(v.z, v.w);
  }
  __syncthreads();
#pragma unroll
  for (int c = 0; c < 2; c++) {
    int q = tid + c * 256;
    int d = q >> 3, c8 = q & 7;
    unsigned short tmp[8];
#pragma unroll
    for (int jj = 0; jj < 8; jj++) tmp[jj] = tile[(c8 * 8 + jj) * 68 + d];
    *(uint4*)(Vt + ((size_t)bh * 64 + d) * 2368 + ct * 64 + c8 * 8) = *(uint4*)tmp;
  }
}

// ---------------- flash attention, KV-split=4, no-max softmax, XOR-swizzled LDS ----------------
// LDS element (r,c) at r*64 + (((c>>3)^(r&7))<<3) + (c&7): 32 KiB total -> 5 blocks/CU.
__global__ __launch_bounds__(256) void attn_kernel(
    const unsigned short* __restrict__ Qb, const unsigned short* __restrict__ Kb,
    const unsigned short* __restrict__ Vt,
    unsigned short* __restrict__ Opart, float* __restrict__ Lbuf) {
  __shared__ __attribute__((aligned(16))) unsigned short Ks[64 * 64];
  __shared__ __attribute__((aligned(16))) unsigned short Vts[64 * 64];  // [dh][key]
  __shared__ __attribute__((aligned(16))) unsigned short Ps[128 * 64];
  int qt = blockIdx.x, bh = blockIdx.y, sp = blockIdx.z;
  int m0 = qt * 128;
  int kt0 = (37 * sp) >> 2, kt1 = (37 * (sp + 1)) >> 2;  // 9/9/9/10
  const unsigned short* Qh = Qb + (size_t)bh * 2304 * 64;
  const unsigned short* Kh = Kb + (size_t)bh * 2308 * 64;
  const unsigned short* VtH = Vt + (size_t)bh * 64 * 2368;
  int tid = threadIdx.x, lane = tid & 63, wave = tid >> 6;
  int quad = lane >> 4, l15 = lane & 15;
  const float CS = 0.18033688011112042f;  // 0.125 * log2(e)

  short8 qf[2][2];
#pragma unroll
  for (int i = 0; i < 2; i++)
#pragma unroll
    for (int s = 0; s < 2; s++)
      qf[i][s] = *(const short8*)(Qh + (size_t)(m0 + wave * 32 + i * 16 + l15) * 64 + s * 32 + quad * 8);

  f32x4 oacc[2][4] = {};
  float lsum[2][4] = {};

  for (int kt = kt0; kt < kt1; kt++) {
    __syncthreads();  // prior QK/PV reads of Ks/Vts done
#pragma unroll
    for (int c = 0; c < 2; c++) {
      int q = tid + c * 256;
      int krow = q >> 3, c8 = q & 7;
      int sw = ((c8 ^ (krow & 7)) << 3);
      int gk = kt * 64 + krow;
      uint4 kv = make_uint4(0, 0, 0, 0);
      if (gk < 2308) kv = *(const uint4*)(Kh + (size_t)gk * 64 + c8 * 8);
      *(uint4*)(Ks + krow * 64 + sw) = kv;
      uint4 vv = *(const uint4*)(VtH + (size_t)krow * 2368 + kt * 64 + c8 * 8);  // krow is d here
      *(uint4*)(Vts + krow * 64 + sw) = vv;
    }
    __syncthreads();  // staging visible
    // S = Q K^T
    f32x4 sacc[2][4] = {};
#pragma unroll
    for (int s = 0; s < 2; s++) {
      short8 kf[4];
#pragma unroll
      for (int j = 0; j < 4; j++) {
        int rr = j * 16 + l15, cb = s * 4 + quad;
        kf[j] = *(const short8*)(Ks + rr * 64 + ((cb ^ (rr & 7)) << 3));
      }
#pragma unroll
      for (int i = 0; i < 2; i++)
#pragma unroll
        for (int j = 0; j < 4; j++)
          sacc[i][j] = __builtin_amdgcn_mfma_f32_16x16x32_bf16(qf[i][s], kf[j], sacc[i][j], 0, 0, 0);
    }
    if (kt == 36) {  // mask cols >= 2308 -> p = exp2(-huge) = 0
#pragma unroll
      for (int j = 0; j < 4; j++) {
        bool ok = (kt * 64 + j * 16 + l15) < 2308;
        if (!ok) {
#pragma unroll
          for (int i = 0; i < 2; i++)
#pragma unroll
            for (int r = 0; r < 4; r++) sacc[i][j][r] = -1e30f;
        }
      }
    }
    // softmax numerator, no max-subtraction, no cross-lane ops
#pragma unroll
    for (int i = 0; i < 2; i++) {
#pragma unroll
      for (int r = 0; r < 4; r++) {
        int prow = wave * 32 + i * 16 + quad * 4 + r;
        int pswz = prow & 7;
#pragma unroll
        for (int j = 0; j < 4; j++) {
          float p = exp2f(sacc[i][j][r] * CS);
          lsum[i][r] += p;
          int col = j * 16 + l15;
          Ps[prow * 64 + (((col >> 3) ^ pswz) << 3) + (col & 7)] = f2bf(p);
        }
      }
    }
    // O += P V  (Ps rows are wave-local; DS ops in-order per wave -> no barrier needed)
#pragma unroll
    for (int s = 0; s < 2; s++) {
      short8 ap[2];
#pragma unroll
      for (int i = 0; i < 2; i++) {
        int ar = wave * 32 + i * 16 + l15, cb = s * 4 + quad;
        ap[i] = *(const short8*)(Ps + ar * 64 + ((cb ^ (ar & 7)) << 3));
      }
#pragma unroll
      for (int jo = 0; jo < 4; jo++) {
        int vr = jo * 16 + l15, cb = s * 4 + quad;
        short8 bv = *(const short8*)(Vts + vr * 64 + ((cb ^ (vr & 7)) << 3));
#pragma unroll
        for (int i = 0; i < 2; i++)
          oacc[i][jo] = __builtin_amdgcn_mfma_f32_16x16x32_bf16(ap[i], bv, oacc[i][jo], 0, 0, 0);
      }
    }
  }
  // one-time cross-lane reduce of row sums (16 lanes per quad hold partials of same row)
#pragma unroll
  for (int i = 0; i < 2; i++)
#pragma unroll
    for (int r = 0; r < 4; r++) {
      float v = lsum[i][r];
#pragma unroll
      for (int o = 1; o < 16; o <<= 1) v += __shfl_xor(v, o);
      lsum[i][r] = v;
    }
  size_t obase = (size_t)(sp * 16 + bh) * 2304;
#pragma unroll
  for (int i = 0; i < 2; i++) {
#pragma unroll
    for (int r = 0; r < 4; r++) {
      int row = m0 + wave * 32 + i * 16 + quad * 4 + r;
#pragma unroll
      for (int jo = 0; jo < 4; jo++)
        Opart[(obase + row) * 64 + jo * 16 + l15] = f2bf(oacc[i][jo][r]);
      if (l15 == 0) Lbuf[obase + row] = lsum[i][r];
    }
  }
}

// ---------------- combine 4 splits -> Ot (plain sums; shared softmax basis) ----------------
__global__ __launch_bounds__(256) void combine_kernel(
    const unsigned short* __restrict__ Opart, const float* __restrict__ Lbuf,
    unsigned short* __restrict__ Ot) {
  int rg = blockIdx.x * 4 + (threadIdx.x >> 6);  // global row index 0..36863
  int d = threadIdx.x & 63;
  int bh = rg / 2304, row = rg - bh * 2304;
  int b = bh >> 3, h = bh & 7;
  float num = 0.f, den = 0.f;
#pragma unroll
  for (int s = 0; s < 4; s++) {
    size_t ri = ((size_t)(s * 16 + bh) * 2304 + row);
    den += Lbuf[ri];
    num += bf2f(Opart[ri * 64 + d]);
  }
  Ot[((size_t)(b * 2304 + row)) * 512 + h * 64 + d] = f2bf(num / den);
}

// ---------------- GEMM2: y = O @ wout^T + b, async LDS staging ----------------
__global__ __launch_bounds__(256) void gemm_out_kernel(
    const unsigned short* __restrict__ A, const unsigned short* __restrict__ Bw,
    const float* __restrict__ bias, float* __restrict__ y) {
  __shared__ __attribute__((aligned(16))) unsigned short As[128 * 32];
  __shared__ __attribute__((aligned(16))) unsigned short Bs[128 * 32];
  int m0 = blockIdx.x * 128, o0 = blockIdx.y * 128;
  int tid = threadIdx.x, lane = tid & 63, wave = tid >> 6;
  int quad = lane >> 4, l15 = lane & 15;
  int wm = wave & 1, wn = wave >> 1;
  f32x4 acc[4][4] = {};
  for (int k0 = 0; k0 < 512; k0 += 32) {
    __syncthreads();
#pragma unroll
    for (int c = 0; c < 2; c++) {
      int q = tid + c * 256;
      int row = q >> 2, cc = q & 3;
      __builtin_amdgcn_global_load_lds(GPTR(A + (size_t)(m0 + row) * 512 + k0 + cc * 8),
                                       LPTR(As + q * 8), 16, 0, 0);
      __builtin_amdgcn_global_load_lds(GPTR(Bw + (size_t)(o0 + row) * 512 + k0 + cc * 8),
                                       LPTR(Bs + q * 8), 16, 0, 0);
    }
    __syncthreads();
    short8 af[4], bf[4];
#pragma unroll
    for (int i = 0; i < 4; i++) af[i] = *(const short8*)(As + (wm * 64 + i * 16 + l15) * 32 + quad * 8);
#pragma unroll
    for (int j = 0; j < 4; j++) bf[j] = *(const short8*)(Bs + (wn * 64 + j * 16 + l15) * 32 + quad * 8);
#pragma unroll
    for (int i = 0; i < 4; i++)
#pragma unroll
      for (int j = 0; j < 4; j++)
        acc[i][j] = __builtin_amdgcn_mfma_f32_16x16x32_bf16(af[i], bf[j], acc[i][j], 0, 0, 0);
  }
#pragma unroll
  for (int i = 0; i < 4; i++) {
#pragma unroll
    for (int j = 0; j < 4; j++) {
      int colo = o0 + wn * 64 + j * 16 + l15;
      float bb = bias[colo];
#pragma unroll
      for (int reg = 0; reg < 4; reg++) {
        int m = m0 + wm * 64 + i * 16 + quad * 4 + reg;
        y[(size_t)m * 512 + colo] = acc[i][j][reg] + bb;
      }
    }
  }
}

// ---------------- GN2 stats stage 1: 256 blocks x 18 rows, coalesced ----------------
__global__ __launch_bounds__(256) void gn2_stats1_kernel(const float* __restrict__ y,
                                                         float2* __restrict__ part2) {
  __shared__ float sg[32], qg[32];
  int bi = blockIdx.x;  // 0..255; 128 blocks per batch; b boundary at bi=128 (row 2304)
  int b = bi >> 7;
  int r0 = bi * 18;
  int t = threadIdx.x;
  if (t < 32) { sg[t] = 0.f; qg[t] = 0.f; }
  __syncthreads();
  int col4 = t & 127, half = t >> 7;
  int grp = col4 >> 2;
  float s = 0.f, q = 0.f;
#pragma unroll
  for (int rp = 0; rp < 18; rp += 2) {
    int rr = rp + half;
    float4 v = *(const float4*)(y + (size_t)(r0 + rr) * 512 + col4 * 4);
    s += v.x + v.y + v.z + v.w;
    q += v.x * v.x + v.y * v.y + v.z * v.z + v.w * v.w;
  }
  atomicAdd(&sg[grp], s);
  atomicAdd(&qg[grp], q);
  __syncthreads();
  if (t < 32) part2[(size_t)(b * 32 + t) * 128 + (bi & 127)] = make_float2(sg[t], qg[t]);
}

// ---------------- GN2 normalize + transpose to (B,C,N); folds stats stage 2 ----------------
__global__ __launch_bounds__(256) void gn2_final_kernel(const float* __restrict__ y,
    const float* __restrict__ gw, const float* __restrict__ gb,
    const float2* __restrict__ part2, float* __restrict__ out) {
  __shared__ float tile[32][33];
  int n0 = blockIdx.x * 32, c0 = blockIdx.y * 32, b = blockIdx.z;
  int g0 = c0 >> 4;
  float mu2[2], rs2[2];
#pragma unroll
  for (int gg = 0; gg < 2; gg++) {
    float s = 0.f, q = 0.f;
    const float2* p = part2 + (size_t)(b * 32 + g0 + gg) * 128;
    for (int k = 0; k < 128; k++) { float2 v = p[k]; s += v.x; q += v.y; }
    float mu = s / 36864.f;
    float var = q / 36864.f - mu * mu;
    mu2[gg] = mu;
    rs2[gg] = rsqrtf(var + 1e-5f);
  }
  int tx = threadIdx.x & 31, ty = threadIdx.x >> 5;
#pragma unroll
  for (int r = 0; r < 4; r++) {
    int n = n0 + ty + r * 8;
    tile[ty + r * 8][tx] = y[((size_t)(b * 2304 + n)) * 512 + c0 + tx];
  }
  __syncthreads();
#pragma unroll
  for (int r = 0; r < 4; r++) {
    int c = c0 + ty + r * 8;
    int gg = (ty + r * 8) >> 4;
    float v = tile[tx][ty + r * 8];
    out[((size_t)(b * 512 + c)) * 2304 + n0 + tx] = (v - mu2[gg]) * rs2[gg] * gw[c] + gb[c];
  }
}

extern "C" void kernel_launch(void* const* d_in, const int* in_sizes, int n_in,
                              void* d_out, int out_size, void* d_ws, size_t ws_size,
                              hipStream_t stream) {
  const float* x     = (const float*)d_in[0];
  const float* gn1w  = (const float*)d_in[1];
  const float* gn1b  = (const float*)d_in[2];
  const float* wqkv  = (const float*)d_in[3];
  const float* memkv = (const float*)d_in[4];
  const float* wout  = (const float*)d_in[5];
  const float* bout  = (const float*)d_in[6];
  const float* gn2w  = (const float*)d_in[7];
  const float* gn2b  = (const float*)d_in[8];
  float* out = (float*)d_out;

  char* ws = (char*)d_ws;
  float2* part1        = (float2*)(ws + 0);                 //   4,096
  float2* part2        = (float2*)(ws + 4096);              //  65,536
  unsigned short* wqB  = (unsigned short*)(ws + 69632);     // 1,572,864
  unsigned short* woB  = (unsigned short*)(ws + 1642496);   //   524,288
  unsigned short* tB   = (unsigned short*)(ws + 2166784);   // 4,718,592
  unsigned short* Qb   = (unsigned short*)(ws + 6885376);   // 4,718,592
  unsigned short* Kb   = (unsigned short*)(ws + 11603968);  // 4,726,784
  unsigned short* Vb   = (unsigned short*)(ws + 16330752);  // 4,726,784
  unsigned short* Ot   = (unsigned short*)(ws + 21057536);  // 4,718,592
  float* y             = (float*)(ws + 25776128);           // 9,437,184
  unsigned short* Vt   = (unsigned short*)(ws + 35213312);  // 4,849,664
  unsigned short* Opart= (unsigned short*)(ws + 40062976);  // 18,874,368
  float* Lbuf          = (float*)(ws + 58937344);           //   589,824
  // total workspace use: 59,527,168 bytes

  prep_gn1_kernel<<<4640, 256, 0, stream>>>(wqkv, wout, memkv, x, wqB, woB, Kb, Vb, part1);
  tnorm_kernel<<<dim3(72, 16, 2), 256, 0, stream>>>(x, gn1w, gn1b, part1, tB);
  gemm_qkv_kernel<<<dim3(36, 12), 256, 0, stream>>>(tB, wqB, Qb, Kb, Vb);
  vt_kernel<<<dim3(37, 16), 256, 0, stream>>>(Vb, Vt);
  attn_kernel<<<dim3(18, 16, 4), 256, 0, stream>>>(Qb, Kb, Vt, Opart, Lbuf);
  combine_kernel<<<9216, 256, 0, stream>>>(Opart, Lbuf, Ot);
  gemm_out_kernel<<<dim3(36, 4), 256, 0, stream>>>(Ot, woB, bout, y);
  gn2_stats1_kernel<<<256, 256, 0, stream>>>(y, part2);
  gn2_final_kernel<<<dim3(72, 16, 2), 256, 0, stream>>>(y, gn2w, gn2b, part2, out);
}

// Round 6
// 193.758 us; speedup vs baseline: 1.0997x; 1.0997x over previous
//
#include <hip/hip_runtime.h>
#include <hip/hip_bf16.h>

typedef short short8 __attribute__((ext_vector_type(8)));
typedef float f32x4 __attribute__((ext_vector_type(4)));

#define GPTR(x) ((const __attribute__((address_space(1))) void*)(x))
#define LPTR(x) ((__attribute__((address_space(3))) void*)(x))

static __device__ __forceinline__ unsigned short f2bf(float f) {
  __hip_bfloat16 h = __float2bfloat16(f);
  return __builtin_bit_cast(unsigned short, h);
}
static __device__ __forceinline__ float bf2f(unsigned short u) {
  unsigned int v = ((unsigned int)u) << 16;
  return __builtin_bit_cast(float, v);
}

// ---------------- block reduction helper ----------------
static __device__ __forceinline__ void block_reduce2(float& s, float& q) {
#pragma unroll
  for (int o = 32; o > 0; o >>= 1) { s += __shfl_down(s, o); q += __shfl_down(q, o); }
  __shared__ float rs[4], rq[4];
  int tid = threadIdx.x;
  if ((tid & 63) == 0) { rs[tid >> 6] = s; rq[tid >> 6] = q; }
  __syncthreads();
  if (tid == 0) {
    s = rs[0] + rs[1] + rs[2] + rs[3];
    q = rq[0] + rq[1] + rq[2] + rq[3];
  }
}

// ---------------- fused prep (weights->bf16, mem-KV scatter) + GN1 stats stage 1 ----------------
__global__ __launch_bounds__(256) void prep_gn1_kernel(
    const float* __restrict__ wqkv, const float* __restrict__ wout,
    const float* __restrict__ memkv, const float* __restrict__ x,
    unsigned short* __restrict__ wq, unsigned short* __restrict__ wo,
    unsigned short* __restrict__ Kb, unsigned short* __restrict__ Vb,
    float2* __restrict__ part1) {
  int blk = blockIdx.x;
  if (blk < 4128) {
    int i = blk * 256 + threadIdx.x;
    if (i < 786432) {
      wq[i] = f2bf(wqkv[i]);
    } else if (i < 1048576) {
      int j = i - 786432;
      wo[j] = f2bf(wout[j]);
    } else if (i < 1056768) {
      int t = i - 1048576;  // (((s*2+b)*8+h)*4+j)*64+d
      int d = t & 63, j = (t >> 6) & 3, h = (t >> 8) & 7, b = (t >> 11) & 1, s = t >> 12;
      unsigned short bv = f2bf(memkv[((s * 8 + h) * 64 + d) * 4 + j]);
      unsigned short* dst = (s == 0) ? Kb : Vb;
      dst[((size_t)(b * 8 + h) * 2308 + j) * 64 + d] = bv;
    }
  } else {
    int bgc = blk - 4128;  // (b*32+g)*8 + chunk
    const float4* base = (const float4*)x + (size_t)bgc * 1152;
    float s = 0.f, q = 0.f;
    for (int i = threadIdx.x; i < 1152; i += 256) {
      float4 v = base[i];
      s += v.x + v.y + v.z + v.w;
      q += v.x * v.x + v.y * v.y + v.z * v.z + v.w * v.w;
    }
    block_reduce2(s, q);
    if (threadIdx.x == 0) part1[bgc] = make_float2(s, q);
  }
}

// ---------------- normalize + transpose -> t_bf16 (token-major); folds stats stage 2 ----------------
__global__ __launch_bounds__(256) void tnorm_kernel(const float* __restrict__ x,
    const float* __restrict__ gw, const float* __restrict__ gb,
    const float2* __restrict__ part1, unsigned short* __restrict__ t) {
  __shared__ float tile[32][33];
  int n0 = blockIdx.x * 32, c0 = blockIdx.y * 32, b = blockIdx.z;
  int g0 = c0 >> 4;
  float mu2[2], rs2[2];
#pragma unroll
  for (int gg = 0; gg < 2; gg++) {
    float s = 0.f, q = 0.f;
    const float2* p = part1 + (size_t)(b * 32 + g0 + gg) * 8;
#pragma unroll
    for (int k = 0; k < 8; k++) { float2 v = p[k]; s += v.x; q += v.y; }
    float mu = s / 36864.f;
    float var = q / 36864.f - mu * mu;
    mu2[gg] = mu;
    rs2[gg] = rsqrtf(var + 1e-5f);
  }
  int tx = threadIdx.x & 31, ty = threadIdx.x >> 5;
#pragma unroll
  for (int r = 0; r < 4; r++) {
    int c = c0 + ty + r * 8;
    tile[ty + r * 8][tx] = x[((size_t)(b * 512 + c)) * 2304 + n0 + tx];
  }
  __syncthreads();
  int gg = tx >> 4;
#pragma unroll
  for (int r = 0; r < 4; r++) {
    int n = n0 + ty + r * 8;
    int c = c0 + tx;
    float v = tile[tx][ty + r * 8];
    t[((size_t)(b * 2304 + n)) * 512 + c] = f2bf((v - mu2[gg]) * rs2[gg] * gw[c] + gb[c]);
  }
}

// ---------------- GEMM1: qkv = t @ wq^T, async LDS staging, scatter Q/K/V ----------------
__global__ __launch_bounds__(256) void gemm_qkv_kernel(
    const unsigned short* __restrict__ A, const unsigned short* __restrict__ Bw,
    unsigned short* __restrict__ Qb, unsigned short* __restrict__ Kb,
    unsigned short* __restrict__ Vb) {
  __shared__ __attribute__((aligned(16))) unsigned short As[128 * 32];
  __shared__ __attribute__((aligned(16))) unsigned short Bs[128 * 32];
  int m0 = blockIdx.x * 128, o0 = blockIdx.y * 128;
  int tid = threadIdx.x, lane = tid & 63, wave = tid >> 6;
  int quad = lane >> 4, l15 = lane & 15;
  int wm = wave & 1, wn = wave >> 1;
  f32x4 acc[4][4] = {};
  for (int k0 = 0; k0 < 512; k0 += 32) {
    __syncthreads();
#pragma unroll
    for (int c = 0; c < 2; c++) {
      int q = tid + c * 256;
      int row = q >> 2, cc = q & 3;
      __builtin_amdgcn_global_load_lds(GPTR(A + (size_t)(m0 + row) * 512 + k0 + cc * 8),
                                       LPTR(As + q * 8), 16, 0, 0);
      __builtin_amdgcn_global_load_lds(GPTR(Bw + (size_t)(o0 + row) * 512 + k0 + cc * 8),
                                       LPTR(Bs + q * 8), 16, 0, 0);
    }
    __syncthreads();
    short8 af[4], bf[4];
#pragma unroll
    for (int i = 0; i < 4; i++) af[i] = *(const short8*)(As + (wm * 64 + i * 16 + l15) * 32 + quad * 8);
#pragma unroll
    for (int j = 0; j < 4; j++) bf[j] = *(const short8*)(Bs + (wn * 64 + j * 16 + l15) * 32 + quad * 8);
#pragma unroll
    for (int i = 0; i < 4; i++)
#pragma unroll
      for (int j = 0; j < 4; j++)
        acc[i][j] = __builtin_amdgcn_mfma_f32_16x16x32_bf16(af[i], bf[j], acc[i][j], 0, 0, 0);
  }
#pragma unroll
  for (int i = 0; i < 4; i++) {
#pragma unroll
    for (int j = 0; j < 4; j++) {
      int colo = o0 + wn * 64 + j * 16 + l15;
      int part = colo >> 9, rr = colo & 511, h = rr >> 6, d = rr & 63;
#pragma unroll
      for (int reg = 0; reg < 4; reg++) {
        int m = m0 + wm * 64 + i * 16 + quad * 4 + reg;
        int b = (m >= 2304) ? 1 : 0;
        int n = m - b * 2304;
        unsigned short bv = f2bf(acc[i][j][reg]);
        if (part == 0)      Qb[((size_t)(b * 8 + h) * 2304 + n) * 64 + d] = bv;
        else if (part == 1) Kb[((size_t)(b * 8 + h) * 2308 + 4 + n) * 64 + d] = bv;
        else                Vb[((size_t)(b * 8 + h) * 2308 + 4 + n) * 64 + d] = bv;
      }
    }
  }
}

// ---------------- V transpose: Vb [bh][nk][64] -> Vt [bh][64][2368] ----------------
__global__ __launch_bounds__(256) void vt_kernel(const unsigned short* __restrict__ Vb,
                                                 unsigned short* __restrict__ Vt) {
  __shared__ unsigned short tile[64 * 68];
  int ct = blockIdx.x, bh = blockIdx.y;
  int tid = threadIdx.x;
#pragma unroll
  for (int c = 0; c < 2; c++) {
    int q = tid + c * 256;
    int row = q >> 3, c8 = q & 7;
    int gk = ct * 64 + row;
    uint4 v = make_uint4(0, 0, 0, 0);
    if (gk < 2308) v = *(const uint4*)(Vb + ((size_t)bh * 2308 + gk) * 64 + c8 * 8);
    *(uint2*)(tile + row * 68 + c8 * 8)     = make_uint2(v.x, v.y);
    *(uint2*)(tile + row * 68 + c8 * 8 + 4) = make_uint2(v.z, v.w);
  }
  __syncthreads();
#pragma unroll
  for (int c = 0; c < 2; c++) {
    int q = tid + c * 256;
    int d = q >> 3, c8 = q & 7;
    unsigned short tmp[8];
#pragma unroll
    for (int jj = 0; jj < 8; jj++) tmp[jj] = tile[(c8 * 8 + jj) * 68 + d];
    *(uint4*)(Vt + ((size_t)bh * 64 + d) * 2368 + ct * 64 + c8 * 8) = *(uint4*)tmp;
  }
}

// ---------------- flash attention, KV-split=4, no-max softmax (R4 version: pad-72) ----------------
__global__ __launch_bounds__(256) void attn_kernel(
    const unsigned short* __restrict__ Qb, const unsigned short* __restrict__ Kb,
    const unsigned short* __restrict__ Vt,
    unsigned short* __restrict__ Opart, float* __restrict__ Lbuf) {
  __shared__ __attribute__((aligned(16))) unsigned short Ks[64 * 72];
  __shared__ __attribute__((aligned(16))) unsigned short Vts[64 * 72];  // [dh][key]
  __shared__ __attribute__((aligned(16))) unsigned short Ps[128 * 72];
  int qt = blockIdx.x, bh = blockIdx.y, sp = blockIdx.z;
  int m0 = qt * 128;
  int kt0 = sp * 10, kt1 = (kt0 + 10 < 37) ? kt0 + 10 : 37;
  const unsigned short* Qh = Qb + (size_t)bh * 2304 * 64;
  const unsigned short* Kh = Kb + (size_t)bh * 2308 * 64;
  const unsigned short* VtH = Vt + (size_t)bh * 64 * 2368;
  int tid = threadIdx.x, lane = tid & 63, wave = tid >> 6;
  int quad = lane >> 4, l15 = lane & 15;
  const float CS = 0.18033688011112042f;  // 0.125 * log2(e)

  short8 qf[2][2];
#pragma unroll
  for (int i = 0; i < 2; i++)
#pragma unroll
    for (int s = 0; s < 2; s++)
      qf[i][s] = *(const short8*)(Qh + (size_t)(m0 + wave * 32 + i * 16 + l15) * 64 + s * 32 + quad * 8);

  f32x4 oacc[2][4] = {};
  float lsum[2][4] = {};

  for (int kt = kt0; kt < kt1; kt++) {
    __syncthreads();  // prior QK/PV reads of Ks/Vts done
#pragma unroll
    for (int c = 0; c < 2; c++) {
      int q = tid + c * 256;
      int krow = q >> 3, c8 = q & 7;
      int gk = kt * 64 + krow;
      uint4 kv = make_uint4(0, 0, 0, 0);
      if (gk < 2308) kv = *(const uint4*)(Kh + (size_t)gk * 64 + c8 * 8);
      *(uint4*)(Ks + krow * 72 + c8 * 8) = kv;
      uint4 vv = *(const uint4*)(VtH + (size_t)krow * 2368 + kt * 64 + c8 * 8);  // krow is d here
      *(uint4*)(Vts + krow * 72 + c8 * 8) = vv;
    }
    __syncthreads();  // staging visible
    // S = Q K^T
    f32x4 sacc[2][4] = {};
#pragma unroll
    for (int s = 0; s < 2; s++) {
      short8 kf[4];
#pragma unroll
      for (int j = 0; j < 4; j++) kf[j] = *(const short8*)(Ks + (j * 16 + l15) * 72 + s * 32 + quad * 8);
#pragma unroll
      for (int i = 0; i < 2; i++)
#pragma unroll
        for (int j = 0; j < 4; j++)
          sacc[i][j] = __builtin_amdgcn_mfma_f32_16x16x32_bf16(qf[i][s], kf[j], sacc[i][j], 0, 0, 0);
    }
    if (kt == 36) {  // mask cols >= 2308 -> p = exp2(-huge) = 0
#pragma unroll
      for (int j = 0; j < 4; j++) {
        bool ok = (kt * 64 + j * 16 + l15) < 2308;
        if (!ok) {
#pragma unroll
          for (int i = 0; i < 2; i++)
#pragma unroll
            for (int r = 0; r < 4; r++) sacc[i][j][r] = -1e30f;
        }
      }
    }
    // softmax numerator, no max-subtraction, no cross-lane ops
#pragma unroll
    for (int i = 0; i < 2; i++) {
#pragma unroll
      for (int r = 0; r < 4; r++) {
        int prow = (wave * 32 + i * 16 + quad * 4 + r) * 72;
#pragma unroll
        for (int j = 0; j < 4; j++) {
          float p = exp2f(sacc[i][j][r] * CS);
          lsum[i][r] += p;
          Ps[prow + j * 16 + l15] = f2bf(p);
        }
      }
    }
    // O += P V  (Ps rows are wave-local; DS ops in-order per wave -> no barrier needed)
#pragma unroll
    for (int s = 0; s < 2; s++) {
      short8 ap[2];
#pragma unroll
      for (int i = 0; i < 2; i++)
        ap[i] = *(const short8*)(Ps + (wave * 32 + i * 16 + l15) * 72 + s * 32 + quad * 8);
#pragma unroll
      for (int jo = 0; jo < 4; jo++) {
        short8 bv = *(const short8*)(Vts + (jo * 16 + l15) * 72 + s * 32 + quad * 8);
#pragma unroll
        for (int i = 0; i < 2; i++)
          oacc[i][jo] = __builtin_amdgcn_mfma_f32_16x16x32_bf16(ap[i], bv, oacc[i][jo], 0, 0, 0);
      }
    }
  }
  // one-time cross-lane reduce of row sums (16 lanes per quad hold partials of same row)
#pragma unroll
  for (int i = 0; i < 2; i++)
#pragma unroll
    for (int r = 0; r < 4; r++) {
      float v = lsum[i][r];
#pragma unroll
      for (int o = 1; o < 16; o <<= 1) v += __shfl_xor(v, o);
      lsum[i][r] = v;
    }
  size_t obase = (size_t)(sp * 16 + bh) * 2304;
#pragma unroll
  for (int i = 0; i < 2; i++) {
#pragma unroll
    for (int r = 0; r < 4; r++) {
      int row = m0 + wave * 32 + i * 16 + quad * 4 + r;
#pragma unroll
      for (int jo = 0; jo < 4; jo++)
        Opart[(obase + row) * 64 + jo * 16 + l15] = f2bf(oacc[i][jo][r]);
      if (l15 == 0) Lbuf[obase + row] = lsum[i][r];
    }
  }
}

// ---------------- combine 4 splits -> Ot (plain sums; shared softmax basis) ----------------
__global__ __launch_bounds__(256) void combine_kernel(
    const unsigned short* __restrict__ Opart, const float* __restrict__ Lbuf,
    unsigned short* __restrict__ Ot) {
  int rg = blockIdx.x * 4 + (threadIdx.x >> 6);  // global row index 0..36863
  int d = threadIdx.x & 63;
  int bh = rg / 2304, row = rg - bh * 2304;
  int b = bh >> 3, h = bh & 7;
  float num = 0.f, den = 0.f;
#pragma unroll
  for (int s = 0; s < 4; s++) {
    size_t ri = ((size_t)(s * 16 + bh) * 2304 + row);
    den += Lbuf[ri];
    num += bf2f(Opart[ri * 64 + d]);
  }
  Ot[((size_t)(b * 2304 + row)) * 512 + h * 64 + d] = f2bf(num / den);
}

// ---------------- GEMM2: y = O @ wout^T + b, async staging, fused GN2 stats ----------------
__global__ __launch_bounds__(256) void gemm_out_kernel(
    const unsigned short* __restrict__ A, const unsigned short* __restrict__ Bw,
    const float* __restrict__ bias, float* __restrict__ y,
    float* __restrict__ p2s, float* __restrict__ p2q) {
  __shared__ __attribute__((aligned(16))) unsigned short As[128 * 32];
  __shared__ __attribute__((aligned(16))) unsigned short Bs[128 * 32];
  __shared__ float sgrp[8], qgrp[8];
  int m0 = blockIdx.x * 128, o0 = blockIdx.y * 128;
  int tid = threadIdx.x, lane = tid & 63, wave = tid >> 6;
  int quad = lane >> 4, l15 = lane & 15;
  int wm = wave & 1, wn = wave >> 1;
  if (tid < 8) { sgrp[tid] = 0.f; qgrp[tid] = 0.f; }
  f32x4 acc[4][4] = {};
  for (int k0 = 0; k0 < 512; k0 += 32) {
    __syncthreads();
#pragma unroll
    for (int c = 0; c < 2; c++) {
      int q = tid + c * 256;
      int row = q >> 2, cc = q & 3;
      __builtin_amdgcn_global_load_lds(GPTR(A + (size_t)(m0 + row) * 512 + k0 + cc * 8),
                                       LPTR(As + q * 8), 16, 0, 0);
      __builtin_amdgcn_global_load_lds(GPTR(Bw + (size_t)(o0 + row) * 512 + k0 + cc * 8),
                                       LPTR(Bs + q * 8), 16, 0, 0);
    }
    __syncthreads();
    short8 af[4], bf[4];
#pragma unroll
    for (int i = 0; i < 4; i++) af[i] = *(const short8*)(As + (wm * 64 + i * 16 + l15) * 32 + quad * 8);
#pragma unroll
    for (int j = 0; j < 4; j++) bf[j] = *(const short8*)(Bs + (wn * 64 + j * 16 + l15) * 32 + quad * 8);
#pragma unroll
    for (int i = 0; i < 4; i++)
#pragma unroll
      for (int j = 0; j < 4; j++)
        acc[i][j] = __builtin_amdgcn_mfma_f32_16x16x32_bf16(af[i], bf[j], acc[i][j], 0, 0, 0);
  }
  float ss[4] = {}, qq[4] = {};
#pragma unroll
  for (int i = 0; i < 4; i++) {
#pragma unroll
    for (int j = 0; j < 4; j++) {
      int colo = o0 + wn * 64 + j * 16 + l15;
      float bb = bias[colo];
#pragma unroll
      for (int reg = 0; reg < 4; reg++) {
        int m = m0 + wm * 64 + i * 16 + quad * 4 + reg;
        float v = acc[i][j][reg] + bb;
        y[(size_t)m * 512 + colo] = v;
        ss[j] += v;
        qq[j] += v * v;
      }
    }
  }
  // wave-reduce each column-group partial, then LDS-accumulate, then global atomic
#pragma unroll
  for (int j = 0; j < 4; j++) {
#pragma unroll
    for (int o = 1; o < 64; o <<= 1) { ss[j] += __shfl_xor(ss[j], o); qq[j] += __shfl_xor(qq[j], o); }
  }
  if (lane == 0) {
#pragma unroll
    for (int j = 0; j < 4; j++) {
      atomicAdd(&sgrp[wn * 4 + j], ss[j]);
      atomicAdd(&qgrp[wn * 4 + j], qq[j]);
    }
  }
  __syncthreads();
  if (tid < 8) {
    int b = (m0 >= 2304) ? 1 : 0;
    int g = b * 32 + (o0 >> 4) + tid;
    atomicAdd(&p2s[g], sgrp[tid]);
    atomicAdd(&p2q[g], qgrp[tid]);
  }
}

// ---------------- GN2 normalize + transpose to (B,C,N) ----------------
__global__ __launch_bounds__(256) void gn2_final_kernel(const float* __restrict__ y,
    const float* __restrict__ gw, const float* __restrict__ gb,
    const float* __restrict__ p2s, const float* __restrict__ p2q,
    float* __restrict__ out) {
  __shared__ float tile[32][33];
  int n0 = blockIdx.x * 32, c0 = blockIdx.y * 32, b = blockIdx.z;
  int g0 = c0 >> 4;
  float mu2[2], rs2[2];
#pragma unroll
  for (int gg = 0; gg < 2; gg++) {
    float s = p2s[b * 32 + g0 + gg], q = p2q[b * 32 + g0 + gg];
    float mu = s / 36864.f;
    float var = q / 36864.f - mu * mu;
    mu2[gg] = mu;
    rs2[gg] = rsqrtf(var + 1e-5f);
  }
  int tx = threadIdx.x & 31, ty = threadIdx.x >> 5;
#pragma unroll
  for (int r = 0; r < 4; r++) {
    int n = n0 + ty + r * 8;
    tile[ty + r * 8][tx] = y[((size_t)(b * 2304 + n)) * 512 + c0 + tx];
  }
  __syncthreads();
#pragma unroll
  for (int r = 0; r < 4; r++) {
    int c = c0 + ty + r * 8;
    int gg = (ty + r * 8) >> 4;
    float v = tile[tx][ty + r * 8];
    out[((size_t)(b * 512 + c)) * 2304 + n0 + tx] = (v - mu2[gg]) * rs2[gg] * gw[c] + gb[c];
  }
}

extern "C" void kernel_launch(void* const* d_in, const int* in_sizes, int n_in,
                              void* d_out, int out_size, void* d_ws, size_t ws_size,
                              hipStream_t stream) {
  const float* x     = (const float*)d_in[0];
  const float* gn1w  = (const float*)d_in[1];
  const float* gn1b  = (const float*)d_in[2];
  const float* wqkv  = (const float*)d_in[3];
  const float* memkv = (const float*)d_in[4];
  const float* wout  = (const float*)d_in[5];
  const float* bout  = (const float*)d_in[6];
  const float* gn2w  = (const float*)d_in[7];
  const float* gn2b  = (const float*)d_in[8];
  float* out = (float*)d_out;

  char* ws = (char*)d_ws;
  float2* part1        = (float2*)(ws + 0);                 //   4,096
  float* p2s           = (float*)(ws + 4096);               //     256
  float* p2q           = (float*)(ws + 4352);               //     256
  unsigned short* wqB  = (unsigned short*)(ws + 69632);     // 1,572,864
  unsigned short* woB  = (unsigned short*)(ws + 1642496);   //   524,288
  unsigned short* tB   = (unsigned short*)(ws + 2166784);   // 4,718,592
  unsigned short* Qb   = (unsigned short*)(ws + 6885376);   // 4,718,592
  unsigned short* Kb   = (unsigned short*)(ws + 11603968);  // 4,726,784
  unsigned short* Vb   = (unsigned short*)(ws + 16330752);  // 4,726,784
  unsigned short* Ot   = (unsigned short*)(ws + 21057536);  // 4,718,592
  float* y             = (float*)(ws + 25776128);           // 9,437,184
  unsigned short* Vt   = (unsigned short*)(ws + 35213312);  // 4,849,664
  unsigned short* Opart= (unsigned short*)(ws + 40062976);  // 18,874,368
  float* Lbuf          = (float*)(ws + 58937344);           //   589,824
  // total workspace use: 59,527,168 bytes

  prep_gn1_kernel<<<4640, 256, 0, stream>>>(wqkv, wout, memkv, x, wqB, woB, Kb, Vb, part1);
  tnorm_kernel<<<dim3(72, 16, 2), 256, 0, stream>>>(x, gn1w, gn1b, part1, tB);
  gemm_qkv_kernel<<<dim3(36, 12), 256, 0, stream>>>(tB, wqB, Qb, Kb, Vb);
  vt_kernel<<<dim3(37, 16), 256, 0, stream>>>(Vb, Vt);
  attn_kernel<<<dim3(18, 16, 4), 256, 0, stream>>>(Qb, Kb, Vt, Opart, Lbuf);
  combine_kernel<<<9216, 256, 0, stream>>>(Opart, Lbuf, Ot);
  hipMemsetAsync(ws + 4096, 0, 512, stream);
  gemm_out_kernel<<<dim3(36, 4), 256, 0, stream>>>(Ot, woB, bout, y, p2s, p2q);
  gn2_final_kernel<<<dim3(72, 16, 2), 256, 0, stream>>>(y, gn2w, gn2b, p2s, p2q, out);
}

// Round 7
// 182.234 us; speedup vs baseline: 1.1693x; 1.0632x over previous
//
#include <hip/hip_runtime.h>
#include <hip/hip_bf16.h>

typedef short short8 __attribute__((ext_vector_type(8)));
typedef float f32x4 __attribute__((ext_vector_type(4)));

#define GPTR(x) ((const __attribute__((address_space(1))) void*)(x))
#define LPTR(x) ((__attribute__((address_space(3))) void*)(x))

static __device__ __forceinline__ unsigned short f2bf(float f) {
  __hip_bfloat16 h = __float2bfloat16(f);
  return __builtin_bit_cast(unsigned short, h);
}
static __device__ __forceinline__ float bf2f(unsigned short u) {
  unsigned int v = ((unsigned int)u) << 16;
  return __builtin_bit_cast(float, v);
}

// ---------------- block reduction helper ----------------
static __device__ __forceinline__ void block_reduce2(float& s, float& q) {
#pragma unroll
  for (int o = 32; o > 0; o >>= 1) { s += __shfl_down(s, o); q += __shfl_down(q, o); }
  __shared__ float rs[4], rq[4];
  int tid = threadIdx.x;
  if ((tid & 63) == 0) { rs[tid >> 6] = s; rq[tid >> 6] = q; }
  __syncthreads();
  if (tid == 0) {
    s = rs[0] + rs[1] + rs[2] + rs[3];
    q = rq[0] + rq[1] + rq[2] + rq[3];
  }
}

// ---------------- GN1 stats stage 1: 512 blocks ----------------
__global__ __launch_bounds__(256) void gn1_stats_kernel(const float* __restrict__ x,
                                                        float2* __restrict__ part1) {
  int bgc = blockIdx.x;  // (b*32+g)*8 + chunk
  const float4* base = (const float4*)x + (size_t)bgc * 1152;
  float s = 0.f, q = 0.f;
  for (int i = threadIdx.x; i < 1152; i += 256) {
    float4 v = base[i];
    s += v.x + v.y + v.z + v.w;
    q += v.x * v.x + v.y * v.y + v.z * v.z + v.w * v.w;
  }
  block_reduce2(s, q);
  if (threadIdx.x == 0) part1[bgc] = make_float2(s, q);
}

// ---------------- fused: tnorm (blocks 0..2303) + weight prep / mem-KV (blocks 2304..6431) ----------------
__global__ __launch_bounds__(256) void tnorm_prep_kernel(const float* __restrict__ x,
    const float* __restrict__ gw, const float* __restrict__ gb,
    const float2* __restrict__ part1, unsigned short* __restrict__ t,
    const float* __restrict__ wqkv, const float* __restrict__ wout,
    const float* __restrict__ memkv,
    unsigned short* __restrict__ wq, unsigned short* __restrict__ wo,
    unsigned short* __restrict__ Kb, unsigned short* __restrict__ Vt) {
  __shared__ float tile[32][33];
  int blk = blockIdx.x;
  if (blk < 2304) {
    int n0 = (blk % 72) * 32, c0 = ((blk / 72) & 15) * 32, b = blk / 1152;
    int g0 = c0 >> 4;
    float mu2[2], rs2[2];
#pragma unroll
    for (int gg = 0; gg < 2; gg++) {
      float s = 0.f, q = 0.f;
      const float2* p = part1 + (size_t)(b * 32 + g0 + gg) * 8;
#pragma unroll
      for (int k = 0; k < 8; k++) { float2 v = p[k]; s += v.x; q += v.y; }
      float mu = s / 36864.f;
      float var = q / 36864.f - mu * mu;
      mu2[gg] = mu;
      rs2[gg] = rsqrtf(var + 1e-5f);
    }
    int tx = threadIdx.x & 31, ty = threadIdx.x >> 5;
#pragma unroll
    for (int r = 0; r < 4; r++) {
      int c = c0 + ty + r * 8;
      tile[ty + r * 8][tx] = x[((size_t)(b * 512 + c)) * 2304 + n0 + tx];
    }
    __syncthreads();
    int gg = tx >> 4;
#pragma unroll
    for (int r = 0; r < 4; r++) {
      int n = n0 + ty + r * 8;
      int c = c0 + tx;
      float v = tile[tx][ty + r * 8];
      t[((size_t)(b * 2304 + n)) * 512 + c] = f2bf((v - mu2[gg]) * rs2[gg] * gw[c] + gb[c]);
    }
  } else {
    int i = (blk - 2304) * 256 + threadIdx.x;
    if (i < 786432) {
      wq[i] = f2bf(wqkv[i]);
    } else if (i < 1048576) {
      int j = i - 786432;
      wo[j] = f2bf(wout[j]);
    } else if (i < 1056768) {
      int tt = i - 1048576;  // (((s*2+b)*8+h)*4+j)*64+d
      int d = tt & 63, j = (tt >> 6) & 3, h = (tt >> 8) & 7, b = (tt >> 11) & 1, s = tt >> 12;
      unsigned short bv = f2bf(memkv[((s * 8 + h) * 64 + d) * 4 + j]);
      if (s == 0) Kb[((size_t)(b * 8 + h) * 2308 + j) * 64 + d] = bv;
      else        Vt[((size_t)(b * 8 + h) * 64 + d) * 2368 + j] = bv;
    }
  }
}

// ---------------- GEMM1: qkv = t @ wq^T, async staging; Q/K row-major, V direct-transposed ----------------
__global__ __launch_bounds__(256) void gemm_qkv_kernel(
    const unsigned short* __restrict__ A, const unsigned short* __restrict__ Bw,
    unsigned short* __restrict__ Qb, unsigned short* __restrict__ Kb,
    unsigned short* __restrict__ Vt) {
  __shared__ __attribute__((aligned(16))) unsigned short As[128 * 32];
  __shared__ __attribute__((aligned(16))) unsigned short Bs[128 * 32];
  int m0 = blockIdx.x * 128, o0 = blockIdx.y * 128;
  int tid = threadIdx.x, lane = tid & 63, wave = tid >> 6;
  int quad = lane >> 4, l15 = lane & 15;
  int wm = wave & 1, wn = wave >> 1;
  f32x4 acc[4][4] = {};
  for (int k0 = 0; k0 < 512; k0 += 32) {
    __syncthreads();
#pragma unroll
    for (int c = 0; c < 2; c++) {
      int q = tid + c * 256;
      int row = q >> 2, cc = q & 3;
      __builtin_amdgcn_global_load_lds(GPTR(A + (size_t)(m0 + row) * 512 + k0 + cc * 8),
                                       LPTR(As + q * 8), 16, 0, 0);
      __builtin_amdgcn_global_load_lds(GPTR(Bw + (size_t)(o0 + row) * 512 + k0 + cc * 8),
                                       LPTR(Bs + q * 8), 16, 0, 0);
    }
    __syncthreads();
    short8 af[4], bf[4];
#pragma unroll
    for (int i = 0; i < 4; i++) af[i] = *(const short8*)(As + (wm * 64 + i * 16 + l15) * 32 + quad * 8);
#pragma unroll
    for (int j = 0; j < 4; j++) bf[j] = *(const short8*)(Bs + (wn * 64 + j * 16 + l15) * 32 + quad * 8);
#pragma unroll
    for (int i = 0; i < 4; i++)
#pragma unroll
      for (int j = 0; j < 4; j++)
        acc[i][j] = __builtin_amdgcn_mfma_f32_16x16x32_bf16(af[i], bf[j], acc[i][j], 0, 0, 0);
  }
#pragma unroll
  for (int i = 0; i < 4; i++) {
#pragma unroll
    for (int j = 0; j < 4; j++) {
      int colo = o0 + wn * 64 + j * 16 + l15;
      int part = colo >> 9, rr = colo & 511, h = rr >> 6, d = rr & 63;
      int mbase = m0 + wm * 64 + i * 16 + quad * 4;
      int b = (mbase >= 2304) ? 1 : 0;
      int n = mbase - b * 2304;
      unsigned short bv[4];
#pragma unroll
      for (int reg = 0; reg < 4; reg++) bv[reg] = f2bf(acc[i][j][reg]);
      if (part == 0) {
#pragma unroll
        for (int reg = 0; reg < 4; reg++)
          Qb[((size_t)(b * 8 + h) * 2304 + n + reg) * 64 + d] = bv[reg];
      } else if (part == 1) {
#pragma unroll
        for (int reg = 0; reg < 4; reg++)
          Kb[((size_t)(b * 8 + h) * 2308 + 4 + n + reg) * 64 + d] = bv[reg];
      } else {
        unsigned long long pk = (unsigned long long)bv[0] | ((unsigned long long)bv[1] << 16) |
                                ((unsigned long long)bv[2] << 32) | ((unsigned long long)bv[3] << 48);
        *(unsigned long long*)(Vt + ((size_t)(b * 8 + h) * 64 + d) * 2368 + 4 + n) = pk;
      }
    }
  }
}

// ---------------- flash attention, KV-split=4, no-max softmax (frozen R4/R6 version) ----------------
__global__ __launch_bounds__(256) void attn_kernel(
    const unsigned short* __restrict__ Qb, const unsigned short* __restrict__ Kb,
    const unsigned short* __restrict__ Vt,
    unsigned short* __restrict__ Opart, float* __restrict__ Lbuf) {
  __shared__ __attribute__((aligned(16))) unsigned short Ks[64 * 72];
  __shared__ __attribute__((aligned(16))) unsigned short Vts[64 * 72];  // [dh][key]
  __shared__ __attribute__((aligned(16))) unsigned short Ps[128 * 72];
  int qt = blockIdx.x, bh = blockIdx.y, sp = blockIdx.z;
  int m0 = qt * 128;
  int kt0 = sp * 10, kt1 = (kt0 + 10 < 37) ? kt0 + 10 : 37;
  const unsigned short* Qh = Qb + (size_t)bh * 2304 * 64;
  const unsigned short* Kh = Kb + (size_t)bh * 2308 * 64;
  const unsigned short* VtH = Vt + (size_t)bh * 64 * 2368;
  int tid = threadIdx.x, lane = tid & 63, wave = tid >> 6;
  int quad = lane >> 4, l15 = lane & 15;
  const float CS = 0.18033688011112042f;  // 0.125 * log2(e)

  short8 qf[2][2];
#pragma unroll
  for (int i = 0; i < 2; i++)
#pragma unroll
    for (int s = 0; s < 2; s++)
      qf[i][s] = *(const short8*)(Qh + (size_t)(m0 + wave * 32 + i * 16 + l15) * 64 + s * 32 + quad * 8);

  f32x4 oacc[2][4] = {};
  float lsum[2][4] = {};

  for (int kt = kt0; kt < kt1; kt++) {
    __syncthreads();  // prior QK/PV reads of Ks/Vts done
#pragma unroll
    for (int c = 0; c < 2; c++) {
      int q = tid + c * 256;
      int krow = q >> 3, c8 = q & 7;
      int gk = kt * 64 + krow;
      uint4 kv = make_uint4(0, 0, 0, 0);
      if (gk < 2308) kv = *(const uint4*)(Kh + (size_t)gk * 64 + c8 * 8);
      *(uint4*)(Ks + krow * 72 + c8 * 8) = kv;
      uint4 vv = *(const uint4*)(VtH + (size_t)krow * 2368 + kt * 64 + c8 * 8);  // krow is d here
      *(uint4*)(Vts + krow * 72 + c8 * 8) = vv;
    }
    __syncthreads();  // staging visible
    // S = Q K^T
    f32x4 sacc[2][4] = {};
#pragma unroll
    for (int s = 0; s < 2; s++) {
      short8 kf[4];
#pragma unroll
      for (int j = 0; j < 4; j++) kf[j] = *(const short8*)(Ks + (j * 16 + l15) * 72 + s * 32 + quad * 8);
#pragma unroll
      for (int i = 0; i < 2; i++)
#pragma unroll
        for (int j = 0; j < 4; j++)
          sacc[i][j] = __builtin_amdgcn_mfma_f32_16x16x32_bf16(qf[i][s], kf[j], sacc[i][j], 0, 0, 0);
    }
    if (kt == 36) {  // mask cols >= 2308 -> p = exp2(-huge) = 0
#pragma unroll
      for (int j = 0; j < 4; j++) {
        bool ok = (kt * 64 + j * 16 + l15) < 2308;
        if (!ok) {
#pragma unroll
          for (int i = 0; i < 2; i++)
#pragma unroll
            for (int r = 0; r < 4; r++) sacc[i][j][r] = -1e30f;
        }
      }
    }
    // softmax numerator, no max-subtraction, no cross-lane ops
#pragma unroll
    for (int i = 0; i < 2; i++) {
#pragma unroll
      for (int r = 0; r < 4; r++) {
        int prow = (wave * 32 + i * 16 + quad * 4 + r) * 72;
#pragma unroll
        for (int j = 0; j < 4; j++) {
          float p = exp2f(sacc[i][j][r] * CS);
          lsum[i][r] += p;
          Ps[prow + j * 16 + l15] = f2bf(p);
        }
      }
    }
    // O += P V  (Ps rows are wave-local; DS ops in-order per wave -> no barrier needed)
#pragma unroll
    for (int s = 0; s < 2; s++) {
      short8 ap[2];
#pragma unroll
      for (int i = 0; i < 2; i++)
        ap[i] = *(const short8*)(Ps + (wave * 32 + i * 16 + l15) * 72 + s * 32 + quad * 8);
#pragma unroll
      for (int jo = 0; jo < 4; jo++) {
        short8 bv = *(const short8*)(Vts + (jo * 16 + l15) * 72 + s * 32 + quad * 8);
#pragma unroll
        for (int i = 0; i < 2; i++)
          oacc[i][jo] = __builtin_amdgcn_mfma_f32_16x16x32_bf16(ap[i], bv, oacc[i][jo], 0, 0, 0);
      }
    }
  }
  // one-time cross-lane reduce of row sums (16 lanes per quad hold partials of same row)
#pragma unroll
  for (int i = 0; i < 2; i++)
#pragma unroll
    for (int r = 0; r < 4; r++) {
      float v = lsum[i][r];
#pragma unroll
      for (int o = 1; o < 16; o <<= 1) v += __shfl_xor(v, o);
      lsum[i][r] = v;
    }
  size_t obase = (size_t)(sp * 16 + bh) * 2304;
#pragma unroll
  for (int i = 0; i < 2; i++) {
#pragma unroll
    for (int r = 0; r < 4; r++) {
      int row = m0 + wave * 32 + i * 16 + quad * 4 + r;
#pragma unroll
      for (int jo = 0; jo < 4; jo++)
        Opart[(obase + row) * 64 + jo * 16 + l15] = f2bf(oacc[i][jo][r]);
      if (l15 == 0) Lbuf[obase + row] = lsum[i][r];
    }
  }
}

// ---------------- combine 4 splits -> Ot (vectorized: uint2 = 4 bf16 per thread) ----------------
__global__ __launch_bounds__(256) void combine_kernel(
    const unsigned short* __restrict__ Opart, const float* __restrict__ Lbuf,
    unsigned short* __restrict__ Ot) {
  int t = threadIdx.x;
  int rg = blockIdx.x * 16 + (t >> 4);  // global row index 0..36863
  int d4 = (t & 15) * 4;
  int bh = rg / 2304, row = rg - bh * 2304;
  int b = bh >> 3, h = bh & 7;
  float den = 0.f, num[4] = {};
#pragma unroll
  for (int s = 0; s < 4; s++) {
    size_t ri = ((size_t)(s * 16 + bh) * 2304 + row);
    den += Lbuf[ri];
    uint2 pv = *(const uint2*)(Opart + ri * 64 + d4);
    const unsigned short* pp = (const unsigned short*)&pv;
#pragma unroll
    for (int k = 0; k < 4; k++) num[k] += bf2f(pp[k]);
  }
  float rinv = 1.f / den;
  unsigned short ov[4];
#pragma unroll
  for (int k = 0; k < 4; k++) ov[k] = f2bf(num[k] * rinv);
  *(uint2*)(Ot + ((size_t)(b * 2304 + row)) * 512 + h * 64 + d4) = *(uint2*)ov;
}

// ---------------- GEMM2: y = O @ wout^T + b, async staging, fused GN2 stats ----------------
__global__ __launch_bounds__(256) void gemm_out_kernel(
    const unsigned short* __restrict__ A, const unsigned short* __restrict__ Bw,
    const float* __restrict__ bias, float* __restrict__ y,
    float* __restrict__ p2s, float* __restrict__ p2q) {
  __shared__ __attribute__((aligned(16))) unsigned short As[128 * 32];
  __shared__ __attribute__((aligned(16))) unsigned short Bs[128 * 32];
  __shared__ float sgrp[8], qgrp[8];
  int m0 = blockIdx.x * 128, o0 = blockIdx.y * 128;
  int tid = threadIdx.x, lane = tid & 63, wave = tid >> 6;
  int quad = lane >> 4, l15 = lane & 15;
  int wm = wave & 1, wn = wave >> 1;
  if (tid < 8) { sgrp[tid] = 0.f; qgrp[tid] = 0.f; }
  f32x4 acc[4][4] = {};
  for (int k0 = 0; k0 < 512; k0 += 32) {
    __syncthreads();
#pragma unroll
    for (int c = 0; c < 2; c++) {
      int q = tid + c * 256;
      int row = q >> 2, cc = q & 3;
      __builtin_amdgcn_global_load_lds(GPTR(A + (size_t)(m0 + row) * 512 + k0 + cc * 8),
                                       LPTR(As + q * 8), 16, 0, 0);
      __builtin_amdgcn_global_load_lds(GPTR(Bw + (size_t)(o0 + row) * 512 + k0 + cc * 8),
                                       LPTR(Bs + q * 8), 16, 0, 0);
    }
    __syncthreads();
    short8 af[4], bf[4];
#pragma unroll
    for (int i = 0; i < 4; i++) af[i] = *(const short8*)(As + (wm * 64 + i * 16 + l15) * 32 + quad * 8);
#pragma unroll
    for (int j = 0; j < 4; j++) bf[j] = *(const short8*)(Bs + (wn * 64 + j * 16 + l15) * 32 + quad * 8);
#pragma unroll
    for (int i = 0; i < 4; i++)
#pragma unroll
      for (int j = 0; j < 4; j++)
        acc[i][j] = __builtin_amdgcn_mfma_f32_16x16x32_bf16(af[i], bf[j], acc[i][j], 0, 0, 0);
  }
  float ss[4] = {}, qq[4] = {};
#pragma unroll
  for (int i = 0; i < 4; i++) {
#pragma unroll
    for (int j = 0; j < 4; j++) {
      int colo = o0 + wn * 64 + j * 16 + l15;
      float bb = bias[colo];
#pragma unroll
      for (int reg = 0; reg < 4; reg++) {
        int m = m0 + wm * 64 + i * 16 + quad * 4 + reg;
        float v = acc[i][j][reg] + bb;
        y[(size_t)m * 512 + colo] = v;
        ss[j] += v;
        qq[j] += v * v;
      }
    }
  }
  // wave-reduce each column-group partial, then LDS-accumulate, then global atomic
#pragma unroll
  for (int j = 0; j < 4; j++) {
#pragma unroll
    for (int o = 1; o < 64; o <<= 1) { ss[j] += __shfl_xor(ss[j], o); qq[j] += __shfl_xor(qq[j], o); }
  }
  if (lane == 0) {
#pragma unroll
    for (int j = 0; j < 4; j++) {
      atomicAdd(&sgrp[wn * 4 + j], ss[j]);
      atomicAdd(&qgrp[wn * 4 + j], qq[j]);
    }
  }
  __syncthreads();
  if (tid < 8) {
    int b = (m0 >= 2304) ? 1 : 0;
    int g = b * 32 + (o0 >> 4) + tid;
    atomicAdd(&p2s[g], sgrp[tid]);
    atomicAdd(&p2q[g], qgrp[tid]);
  }
}

// ---------------- GN2 normalize + transpose to (B,C,N) ----------------
__global__ __launch_bounds__(256) void gn2_final_kernel(const float* __restrict__ y,
    const float* __restrict__ gw, const float* __restrict__ gb,
    const float* __restrict__ p2s, const float* __restrict__ p2q,
    float* __restrict__ out) {
  __shared__ float tile[32][33];
  int n0 = blockIdx.x * 32, c0 = blockIdx.y * 32, b = blockIdx.z;
  int g0 = c0 >> 4;
  float mu2[2], rs2[2];
#pragma unroll
  for (int gg = 0; gg < 2; gg++) {
    float s = p2s[b * 32 + g0 + gg], q = p2q[b * 32 + g0 + gg];
    float mu = s / 36864.f;
    float var = q / 36864.f - mu * mu;
    mu2[gg] = mu;
    rs2[gg] = rsqrtf(var + 1e-5f);
  }
  int tx = threadIdx.x & 31, ty = threadIdx.x >> 5;
#pragma unroll
  for (int r = 0; r < 4; r++) {
    int n = n0 + ty + r * 8;
    tile[ty + r * 8][tx] = y[((size_t)(b * 2304 + n)) * 512 + c0 + tx];
  }
  __syncthreads();
#pragma unroll
  for (int r = 0; r < 4; r++) {
    int c = c0 + ty + r * 8;
    int gg = (ty + r * 8) >> 4;
    float v = tile[tx][ty + r * 8];
    out[((size_t)(b * 512 + c)) * 2304 + n0 + tx] = (v - mu2[gg]) * rs2[gg] * gw[c] + gb[c];
  }
}

extern "C" void kernel_launch(void* const* d_in, const int* in_sizes, int n_in,
                              void* d_out, int out_size, void* d_ws, size_t ws_size,
                              hipStream_t stream) {
  const float* x     = (const float*)d_in[0];
  const float* gn1w  = (const float*)d_in[1];
  const float* gn1b  = (const float*)d_in[2];
  const float* wqkv  = (const float*)d_in[3];
  const float* memkv = (const float*)d_in[4];
  const float* wout  = (const float*)d_in[5];
  const float* bout  = (const float*)d_in[6];
  const float* gn2w  = (const float*)d_in[7];
  const float* gn2b  = (const float*)d_in[8];
  float* out = (float*)d_out;

  char* ws = (char*)d_ws;
  float2* part1        = (float2*)(ws + 0);                 //   4,096
  float* p2s           = (float*)(ws + 4096);               //     256
  float* p2q           = (float*)(ws + 4352);               //     256
  unsigned short* wqB  = (unsigned short*)(ws + 69632);     // 1,572,864
  unsigned short* woB  = (unsigned short*)(ws + 1642496);   //   524,288
  unsigned short* tB   = (unsigned short*)(ws + 2166784);   // 4,718,592
  unsigned short* Qb   = (unsigned short*)(ws + 6885376);   // 4,718,592
  unsigned short* Kb   = (unsigned short*)(ws + 11603968);  // 4,726,784
  unsigned short* Ot   = (unsigned short*)(ws + 21057536);  // 4,718,592
  float* y             = (float*)(ws + 25776128);           // 9,437,184
  unsigned short* Vt   = (unsigned short*)(ws + 35213312);  // 4,849,664
  unsigned short* Opart= (unsigned short*)(ws + 40062976);  // 18,874,368
  float* Lbuf          = (float*)(ws + 58937344);           //   589,824
  // total workspace use: 59,527,168 bytes

  gn1_stats_kernel<<<512, 256, 0, stream>>>(x, part1);
  tnorm_prep_kernel<<<6432, 256, 0, stream>>>(x, gn1w, gn1b, part1, tB,
                                              wqkv, wout, memkv, wqB, woB, Kb, Vt);
  gemm_qkv_kernel<<<dim3(36, 12), 256, 0, stream>>>(tB, wqB, Qb, Kb, Vt);
  attn_kernel<<<dim3(18, 16, 4), 256, 0, stream>>>(Qb, Kb, Vt, Opart, Lbuf);
  combine_kernel<<<2304, 256, 0, stream>>>(Opart, Lbuf, Ot);
  hipMemsetAsync(ws + 4096, 0, 512, stream);
  gemm_out_kernel<<<dim3(36, 4), 256, 0, stream>>>(Ot, woB, bout, y, p2s, p2q);
  gn2_final_kernel<<<dim3(72, 16, 2), 256, 0, stream>>>(y, gn2w, gn2b, p2s, p2q, out);
}